// Round 27
// baseline (95.238 us; speedup 1.0000x reference)
//
#include <hip/hip_runtime.h>
#include <stdint.h>

#define K_TOP 10000
#define N0    98304
#define N1    24576
#define N2    6144
#define N3    1536
#define N4    384
#define NSMALL (N2 + N3 + N4)      // 8064
#define ICAP   16896               // per-level candidate capacity
#define JSPLIT 32
#define PARTL  ((size_t)JSPLIT * ICAP)
#define SLOTS  (2 * ICAP + NSMALL) // 41856 = 1308 * 32
#define MAXGT 2048
#define LUTW   8.0f
#define LUTN   256

struct Ptrs { const float* anc[5]; const float* cls[5]; const float* reg[5]; };

// order-preserving float->uint map (ascending uint == ascending float)
__device__ __forceinline__ unsigned f2ord(float f) {
    unsigned u = __float_as_uint(f);
    return (u & 0x80000000u) ? ~u : (u | 0x80000000u);
}

// K0: zero the two candidate counters (plain kernel; runtime fill kernel has
// a high floor in captured graphs — measured r23/r24).
__global__ void k_zero(unsigned* cntG) {
    if (threadIdx.x < 2) cntG[threadIdx.x] = 0;
}

// K1 "front": 96 lev0-compact + 48 lev1-compact + 32 GT-sort + 1 LUT blocks.
// Compact: inline deterministic sampled threshold; DENSE output via one global
// RMW per block. cand NOT pre-zeroed: downstream masks by cnt.
__global__ void __launch_bounds__(512)
k_front(const float* __restrict__ cls0, const float* __restrict__ cls1,
        unsigned* __restrict__ cntG, unsigned long long* __restrict__ cand,
        const float* __restrict__ gt, const int* __restrict__ numgt,
        float4* __restrict__ sbox, unsigned short* __restrict__ sidxG,
        unsigned* __restrict__ lutG, float* __restrict__ maxwG) {
    unsigned tid = threadIdx.x, wave = tid >> 6, lane = tid & 63u;
    int bi = (int)blockIdx.x;

    if (bi < 144) {
        // ================== compact (lev0: bi<96, lev1: bi-96) ==================
        int lev = (bi < 96) ? 0 : 1;
        int bx  = (bi < 96) ? bi : bi - 96;
        const float* cls = lev ? cls1 : cls0;
        const float4* s4 = (const float4*)cls;
        unsigned nq4     = lev ? 3072u : 4096u;
        unsigned targetS = lev ? 5900u : 1966u;   // 11800 scaled by sample frac

        __shared__ unsigned h[8][256];
        __shared__ unsigned sfx[256];
        __shared__ unsigned sd[2];
        __shared__ unsigned lcnt, gbase;

        for (unsigned i = tid; i < 2048u; i += 512u) ((unsigned*)h)[i] = 0;
        __syncthreads();
        for (unsigned q = tid; q < nq4; q += 512u) {
            float4 v = s4[q];
            atomicAdd(&h[wave][f2ord(v.x) >> 24], 1u);
            atomicAdd(&h[wave][f2ord(v.y) >> 24], 1u);
            atomicAdd(&h[wave][f2ord(v.z) >> 24], 1u);
            atomicAdd(&h[wave][f2ord(v.w) >> 24], 1u);
        }
        __syncthreads();
        if (tid < 256) {
            unsigned s = 0;
            #pragma unroll
            for (int w = 0; w < 8; w++) s += h[w][tid];
            sfx[tid] = s;
        }
        __syncthreads();
        for (int off = 1; off < 256; off <<= 1) {   // inclusive suffix sum
            unsigned v = 0;
            if (tid < 256) v = sfx[tid] + ((tid + off < 256) ? sfx[tid + off] : 0u);
            __syncthreads();
            if (tid < 256) sfx[tid] = v;
            __syncthreads();
        }
        if (tid < 256) {
            unsigned suf = sfx[tid];
            unsigned sufN = (tid < 255) ? sfx[tid + 1] : 0u;
            if (suf >= targetS && sufN < targetS) { sd[0] = tid; sd[1] = targetS - sufN; }
        }
        for (unsigned i = tid; i < 2048u; i += 512u) ((unsigned*)h)[i] = 0;
        __syncthreads();
        unsigned tb = sd[0], remS = sd[1];
        for (unsigned q = tid; q < nq4; q += 512u) {
            float4 v = s4[q];
            unsigned k0 = f2ord(v.x), k1 = f2ord(v.y), k2 = f2ord(v.z), k3 = f2ord(v.w);
            if ((k0 >> 24) == tb) atomicAdd(&h[wave][(k0 >> 16) & 255u], 1u);
            if ((k1 >> 24) == tb) atomicAdd(&h[wave][(k1 >> 16) & 255u], 1u);
            if ((k2 >> 24) == tb) atomicAdd(&h[wave][(k2 >> 16) & 255u], 1u);
            if ((k3 >> 24) == tb) atomicAdd(&h[wave][(k3 >> 16) & 255u], 1u);
        }
        __syncthreads();
        if (tid < 256) {
            unsigned s = 0;
            #pragma unroll
            for (int w = 0; w < 8; w++) s += h[w][tid];
            sfx[tid] = s;
        }
        __syncthreads();
        for (int off = 1; off < 256; off <<= 1) {
            unsigned v = 0;
            if (tid < 256) v = sfx[tid] + ((tid + off < 256) ? sfx[tid + off] : 0u);
            __syncthreads();
            if (tid < 256) sfx[tid] = v;
            __syncthreads();
        }
        if (tid < 256) {
            unsigned suf = sfx[tid];
            unsigned sufN = (tid < 255) ? sfx[tid + 1] : 0u;
            if (suf >= remS && sufN < remS) sd[0] = tid;
        }
        if (tid == 0) lcnt = 0;
        __syncthreads();
        unsigned T = ((tb << 8) | sd[0]) << 16;

        unsigned n = lev ? (unsigned)N1 : (unsigned)N0;
        unsigned iters = lev ? 1u : 2u;
        unsigned long long l0 = 0, l1 = 0;
        unsigned c = 0;
        unsigned i = (unsigned)bx * 512u + tid;
        for (unsigned t = 0; t < iters; t++, i += 96u * 512u) {
            if (i < n) {
                unsigned key = f2ord(cls[i]);
                if (key >= T) {
                    unsigned long long v = ((unsigned long long)key << 32) | (unsigned)(~i);
                    if (c == 0) l0 = v; else l1 = v;
                    c++;
                }
            }
        }
        unsigned ls = 0;
        if (c) ls = atomicAdd(&lcnt, c);
        __syncthreads();
        if (tid == 0) gbase = lcnt ? atomicAdd(&cntG[lev], lcnt) : 0u;
        __syncthreads();
        unsigned b = gbase + ls;
        unsigned long long* cl = cand + (size_t)lev * ICAP;
        if (c > 0 && b + 0 < ICAP) cl[b + 0] = l0;
        if (c > 1 && b + 1 < ICAP) cl[b + 1] = l1;
    } else if (bi < 176) {
        // ===== GT sort by (f2ord(x1), idx): block owns 64 GTs, waves split j =====
        __shared__ __align__(16) unsigned keys[MAXGT];
        __shared__ unsigned prank[8][64];
        int ng = *numgt; if (ng > MAXGT) ng = MAXGT;
        for (int j = (int)tid; j < MAXGT; j += 512)
            keys[j] = (j < ng) ? f2ord(gt[(size_t)j * 5 + 0]) : 0xFFFFFFFFu;
        __syncthreads();
        int i = (bi - 144) * 64 + (int)lane;
        unsigned ki = (i < ng) ? keys[i] : 0xFFFFFFFFu;
        unsigned rank = 0;
        const uint4* k4 = (const uint4*)(keys + wave * 256u);
        #pragma unroll 8
        for (int q = 0; q < 64; q++) {
            uint4 kv = k4[q];
            int j = (int)(wave * 256u) + q * 4;
            rank += (kv.x < ki || (kv.x == ki && j + 0 < i)) ? 1u : 0u;
            rank += (kv.y < ki || (kv.y == ki && j + 1 < i)) ? 1u : 0u;
            rank += (kv.z < ki || (kv.z == ki && j + 2 < i)) ? 1u : 0u;
            rank += (kv.w < ki || (kv.w == ki && j + 3 < i)) ? 1u : 0u;
        }
        prank[wave][lane] = rank;
        __syncthreads();
        if (tid < 64) {
            int ii = (bi - 144) * 64 + (int)tid;
            if (ii < ng) {
                unsigned r = 0;
                #pragma unroll
                for (int w2 = 0; w2 < 8; w2++) r += prank[w2][tid];
                float x1 = gt[(size_t)ii * 5 + 0], y1 = gt[(size_t)ii * 5 + 1];
                float x2 = gt[(size_t)ii * 5 + 2], y2 = gt[(size_t)ii * 5 + 3];
                sbox[r]  = make_float4(x1, y1, x2 + 1.0f, y2 + 1.0f);  // upper +1
                sidxG[r] = (unsigned short)ii;
            }
        }
    } else {
        // ===== bucket LUT (exclusive prefix of x1 histogram) + maxw =====
        __shared__ unsigned hb[LUTN];
        __shared__ unsigned sc[LUTN];
        __shared__ float wm[8];
        int ng = *numgt; if (ng > MAXGT) ng = MAXGT;
        for (unsigned i = tid; i < LUTN; i += 512u) hb[i] = 0;
        __syncthreads();
        float w = 0.f;
        for (int j = (int)tid; j < ng; j += 512) {
            float x1 = gt[(size_t)j * 5 + 0];
            float x2 = gt[(size_t)j * 5 + 2];
            w = fmaxf(w, x2 - x1 + 1.0f);
            int b = (int)(x1 * (1.0f / LUTW));
            if (b < 0) b = 0; if (b > LUTN - 1) b = LUTN - 1;
            atomicAdd(&hb[b], 1u);
        }
        #pragma unroll
        for (int off = 32; off >= 1; off >>= 1) w = fmaxf(w, __shfl_xor(w, off));
        if (lane == 0) wm[wave] = w;
        __syncthreads();
        if (tid < LUTN) sc[tid] = hb[tid];
        __syncthreads();
        for (int off = 1; off < LUTN; off <<= 1) {
            unsigned v = 0;
            if (tid < LUTN) v = sc[tid] + ((int)tid - off >= 0 ? sc[tid - off] : 0u);
            __syncthreads();
            if (tid < LUTN) sc[tid] = v;
            __syncthreads();
        }
        if (tid < LUTN) lutG[tid] = (tid == 0) ? 0u : sc[tid - 1];
        if (tid == 0) {
            lutG[LUTN] = (unsigned)ng;
            float m = wm[0];
            #pragma unroll
            for (int k = 1; k < 8; k++) m = fmaxf(m, wm[k]);
            *maxwG = m;
        }
    }
}

// K2: partial counting-rank, 6 keys/thread (3072 cand per block): each LDS
// tile read serves 12 compares (halves LDS issue vs 3-key). Grid 384 blocks
// (2 lev x 6 ic x 32 jc), blocks past cntP exit. j-tile masked by cnt.
__global__ void __launch_bounds__(512)
k_rank(const unsigned long long* __restrict__ cand, const unsigned* __restrict__ cntG,
       unsigned short* __restrict__ part) {
    unsigned tid = threadIdx.x;
    int bi = (int)blockIdx.x;
    int lev = (bi < 192) ? 0 : 1;
    int idx = (bi < 192) ? bi : bi - 192;
    unsigned ic = (unsigned)(idx >> 5), jc = (unsigned)(idx & 31);
    unsigned cnt = cntG[lev]; if (cnt > ICAP) cnt = ICAP;
    unsigned cntP = (cnt + 63u) & ~63u;           // multiple of 64
    unsigned ibase = ic * 3072u;
    if (ibase >= cntP) return;                    // block-uniform
    const unsigned long long* cl = cand + (size_t)lev * ICAP;
    unsigned long long ci0, ci1, ci2, ci3, ci4, ci5;
    {
        unsigned i0 = ibase + tid;
        ci0 = (i0          < ICAP) ? cl[i0]          : 0ull;
        ci1 = (i0 + 512u   < ICAP) ? cl[i0 + 512u]   : 0ull;
        ci2 = (i0 + 1024u  < ICAP) ? cl[i0 + 1024u]  : 0ull;
        ci3 = (i0 + 1536u  < ICAP) ? cl[i0 + 1536u]  : 0ull;
        ci4 = (i0 + 2048u  < ICAP) ? cl[i0 + 2048u]  : 0ull;
        ci5 = (i0 + 2560u  < ICAP) ? cl[i0 + 2560u]  : 0ull;
    }
    unsigned jch = cntP >> 5;                     // even (cntP % 64 == 0)
    unsigned j0 = jc * jch;
    unsigned lim2 = jch >> 1;                     // <= 264
    __shared__ __align__(16) unsigned long long tile[544];
    if (tid < lim2) {
        ulonglong2 v2 = ((const ulonglong2*)(cl + j0))[tid];
        unsigned jj = j0 + 2u * tid;
        if (jj >= cnt)      v2.x = 0ull;          // mask stale slots
        if (jj + 1u >= cnt) v2.y = 0ull;
        ((ulonglong2*)tile)[tid] = v2;
    }
    __syncthreads();
    unsigned rk0 = 0, rk1 = 0, rk2 = 0, rk3 = 0, rk4 = 0, rk5 = 0;
    const ulonglong2* t2 = (const ulonglong2*)tile;
    #pragma unroll 4
    for (unsigned t = 0; t < lim2; t++) {
        ulonglong2 cj = t2[t];
        rk0 += (cj.x > ci0) ? 1u : 0u; rk0 += (cj.y > ci0) ? 1u : 0u;
        rk1 += (cj.x > ci1) ? 1u : 0u; rk1 += (cj.y > ci1) ? 1u : 0u;
        rk2 += (cj.x > ci2) ? 1u : 0u; rk2 += (cj.y > ci2) ? 1u : 0u;
        rk3 += (cj.x > ci3) ? 1u : 0u; rk3 += (cj.y > ci3) ? 1u : 0u;
        rk4 += (cj.x > ci4) ? 1u : 0u; rk4 += (cj.y > ci4) ? 1u : 0u;
        rk5 += (cj.x > ci5) ? 1u : 0u; rk5 += (cj.y > ci5) ? 1u : 0u;
    }
    unsigned short* pp = part + (lev ? PARTL : 0) + (size_t)jc * ICAP + ibase + tid;
    unsigned i0 = ibase + tid;
    if (i0          < ICAP) pp[0]    = (unsigned short)rk0;
    if (i0 + 512u   < ICAP) pp[512]  = (unsigned short)rk1;
    if (i0 + 1024u  < ICAP) pp[1024] = (unsigned short)rk2;
    if (i0 + 1536u  < ICAP) pp[1536] = (unsigned short)rk3;
    if (i0 + 2048u  < ICAP) pp[2048] = (unsigned short)rk4;
    if (i0 + 2560u  < ICAP) pp[2560] = (unsigned short)rk5;
}

// K3: fused rank-scatter + decode + IoU argmax + targets. Wave owns 4 slots.
// Candidate slots gated by i < cnt (stale cand/part never observed).
__global__ void __launch_bounds__(512)
k_iou(Ptrs p, const unsigned long long* __restrict__ cand,
      const unsigned* __restrict__ cntG,
      const unsigned short* __restrict__ part,
      const float4* __restrict__ sbox, const unsigned short* __restrict__ sidxG,
      const unsigned* __restrict__ lutG, const float* __restrict__ maxwG,
      const float* __restrict__ gt, const int* __restrict__ numgt,
      float* __restrict__ out) {
    __shared__ float4 sg[MAXGT];              // sorted (x1,y1,x2+1,y2+1)  32 KiB
    __shared__ unsigned short sgi[MAXGT];     // 4 KiB
    __shared__ unsigned slut[LUTN + 1];
    int ng = *numgt; if (ng > MAXGT) ng = MAXGT;
    unsigned tid = threadIdx.x;
    for (int j = (int)tid; j < ng; j += 512) { sg[j] = sbox[j]; sgi[j] = sidxG[j]; }
    for (unsigned j = tid; j <= LUTN; j += 512u) slut[j] = lutG[j];
    float maxw = *maxwG;
    __syncthreads();

    unsigned wave = tid >> 6;
    int lane = (int)(tid & 63u);
    unsigned sbase = ((unsigned)blockIdx.x * 8u + wave) * 4u;

    int valid = 0, row = 0;
    float bx1 = 0.f, by1 = 0.f, bx2 = 0.f, by2 = 0.f;
    float dw = 1.f, dh = 1.f, dcx = 0.f, dcy = 0.f;
    if (lane < 4) {
        unsigned s = sbase + (unsigned)lane;
        int lev = 0, ai = 0;
        if (s < 2u * ICAP) {
            lev = (s >= (unsigned)ICAP) ? 1 : 0;
            unsigned i = lev ? (s - ICAP) : s;
            unsigned cnt = cntG[lev]; if (cnt > ICAP) cnt = ICAP;
            if (i < cnt) {
                unsigned long long v = cand[(size_t)lev * ICAP + i];
                const unsigned short* pp = part + (lev ? PARTL : 0) + i;
                unsigned rank = 0;
                #pragma unroll
                for (int j = 0; j < JSPLIT; j++)
                    rank += pp[(size_t)j * ICAP];
                if (rank < K_TOP) {
                    valid = 1;
                    row = lev * K_TOP + (int)rank;
                    ai = (int)~(unsigned)v;
                }
            }
        } else {
            int rr = (int)s - 2 * ICAP;          // < NSMALL by construction
            row = 2 * K_TOP + rr; valid = 1;
            if (rr < N2)           { lev = 2; ai = rr; }
            else if (rr < N2 + N3) { lev = 3; ai = rr - N2; }
            else                   { lev = 4; ai = rr - N2 - N3; }
        }
        if (valid) {
            float4 a4 = ((const float4*)p.anc[lev])[ai];
            float sc = p.cls[lev][ai];
            float4 r4 = *(const float4*)(p.reg[lev] + (size_t)ai * 8);
            dw = a4.z - a4.x + 1.0f;  dh = a4.w - a4.y + 1.0f;
            dcx = a4.x + 0.5f * dw;   dcy = a4.y + 0.5f * dh;
            float pcx = r4.x * dw + dcx, pcy = r4.y * dh + dcy;
            float pw = expf(r4.z) * dw,  ph = expf(r4.w) * dh;
            bx1 = pcx - 0.5f * pw;    by1 = pcy - 0.5f * ph;
            bx2 = pcx + 0.5f * pw - 1.0f;
            by2 = pcy + 0.5f * ph - 1.0f;
            float* o = out + (size_t)row * 10;
            o[0] = bx1; o[1] = by1; o[2] = bx2; o[3] = by2;
            o[4] = 1.0f / (1.0f + expf(-sc));
            o[5] = 1.0f;
        }
    }

    #pragma unroll
    for (int k = 0; k < 4; k++) {
        int vk = __shfl(valid, k, 64);
        if (!vk) continue;                       // wave-uniform
        float kx1 = __shfl(bx1, k, 64), ky1 = __shfl(by1, k, 64);
        float kx2 = __shfl(bx2, k, 64), ky2 = __shfl(by2, k, 64);
        float A = (kx2 - kx1 + 1.0f) * (ky2 - ky1 + 1.0f);
        float x2p = kx2 + 1.0f, y2p = ky2 + 1.0f;
        float vlo = kx1 - maxw - 1.0f;
        float vhi = kx2 + 2.0f;
        int blo = (vlo <= 0.f) ? 0 : (int)(vlo * (1.0f / LUTW));
        if (blo > LUTN - 1) blo = LUTN - 1;
        int bhi = (vhi <= 0.f) ? 0 : ((int)(vhi * (1.0f / LUTW)) + 1);
        if (bhi > LUTN) bhi = LUTN;
        int lo = (int)slut[blo], hi = (int)slut[bhi];

        // iou_a > iou_b <=> I_a*S_b > I_b*S_a  (S = areaBox + areaGT)
        float I = 0.f, S = 1.f;
        int arg = (lane == 0) ? 0 : 0x7FFFFFFF;
        for (int t = lo + lane; t < hi; t += 64) {
            float4 gb = sg[t];
            float iw = fminf(x2p, gb.z) - fmaxf(kx1, gb.x); iw = fmaxf(iw, 0.f);
            float ih = fminf(y2p, gb.w) - fmaxf(ky1, gb.y); ih = fmaxf(ih, 0.f);
            float Ii = iw * ih;
            float Ss = A + (gb.z - gb.x) * (gb.w - gb.y);   // area from folded corners
            float xs = Ii * S, ys = I * Ss;
            int gi = (int)sgi[t];
            if (xs > ys || (xs == ys && gi < arg)) { I = Ii; S = Ss; arg = gi; }
        }
        #pragma unroll
        for (int off = 1; off < 64; off <<= 1) {   // max iou, tie -> min orig idx
            float oI = __shfl_xor(I, off), oS = __shfl_xor(S, off);
            int   oa = __shfl_xor(arg, off);
            float x = oI * S, y = I * oS;
            if (x > y || (x == y && oa < arg)) { I = oI; S = oS; arg = oa; }
        }
        if (lane == k) {
            if (arg >= ng) arg = 0;
            const float* gb = gt + (size_t)arg * 5;   // ORIGINAL coords (exact)
            float gx1 = gb[0], gy1 = gb[1], gx2 = gb[2], gy2 = gb[3];
            float gw = gx2 - gx1 + 1.0f, gh = gy2 - gy1 + 1.0f;
            float gcx = gx1 + 0.5f * gw,  gcy = gy1 + 0.5f * gh;
            float* o = out + (size_t)row * 10;
            o[6] = (gcx - dcx) / dw;
            o[7] = (gcy - dcy) / dh;
            o[8] = logf(gw / dw);
            o[9] = logf(gh / dh);
        }
    }
}

extern "C" void kernel_launch(void* const* d_in, const int* in_sizes, int n_in,
                              void* d_out, int out_size, void* d_ws, size_t ws_size,
                              hipStream_t stream) {
    Ptrs p;
    bool interleaved = (in_sizes[2] == N0 * 8);
    for (int l = 0; l < 5; l++) {
        if (interleaved) {
            p.anc[l] = (const float*)d_in[3 * l + 0];
            p.cls[l] = (const float*)d_in[3 * l + 1];
            p.reg[l] = (const float*)d_in[3 * l + 2];
        } else {
            p.anc[l] = (const float*)d_in[l];
            p.cls[l] = (const float*)d_in[5 + l];
            p.reg[l] = (const float*)d_in[10 + l];
        }
    }
    const float* gt    = (const float*)d_in[15];
    const int*   numgt = (const int*)d_in[16];

    char* ws = (char*)d_ws;
    size_t off = 0;
    unsigned* cntG = (unsigned*)(ws + off);                      off += 256;
    unsigned long long* cand = (unsigned long long*)(ws + off);  off += (size_t)2 * ICAP * 8;           // 264 KiB
    unsigned short* part = (unsigned short*)(ws + off);          off += (size_t)JSPLIT * 2 * ICAP * 2;  // 2.06 MiB
    float4* sbox = (float4*)(ws + off);                          off += (size_t)MAXGT * 16;             // 32 KiB
    unsigned short* sidxG = (unsigned short*)(ws + off);         off += (size_t)MAXGT * 2;              // 4 KiB
    unsigned* lutG = (unsigned*)(ws + off);                      off += (size_t)(LUTN + 4) * 4;
    float* maxwG = (float*)(ws + off);                           off += 256;

    float* out = (float*)d_out;

    k_zero<<<dim3(1), dim3(64), 0, stream>>>(cntG);
    k_front<<<dim3(177), dim3(512), 0, stream>>>(p.cls[0], p.cls[1], cntG, cand,
                                                 gt, numgt, sbox, sidxG, lutG, maxwG);
    k_rank<<<dim3(384), dim3(512), 0, stream>>>(cand, cntG, part);
    k_iou<<<dim3(SLOTS / 32), dim3(512), 0, stream>>>(p, cand, cntG, part, sbox, sidxG,
                                                      lutG, maxwG, gt, numgt, out);
}

// Round 28
// 78.916 us; speedup vs baseline: 1.2068x; 1.2068x over previous
//
#include <hip/hip_runtime.h>
#include <stdint.h>

#define K_TOP 10000
#define N0    98304
#define N1    24576
#define N2    6144
#define N3    1536
#define N4    384
#define NSMALL (N2 + N3 + N4)      // 8064
#define ICAP   16896               // per-level candidate capacity
#define JSPLIT 32
#define PARTL  ((size_t)JSPLIT * ICAP)
#define SLOTS  (2 * ICAP + NSMALL) // 41856 = 1308 * 32
#define MAXGT 2048
#define LUTW   8.0f
#define LUTN   256

struct Ptrs { const float* anc[5]; const float* cls[5]; const float* reg[5]; };

// order-preserving float->uint map (ascending uint == ascending float)
__device__ __forceinline__ unsigned f2ord(float f) {
    unsigned u = __float_as_uint(f);
    return (u & 0x80000000u) ? ~u : (u | 0x80000000u);
}

// K1 "front": 96 lev0-compact + 48 lev1-compact + 32 GT-sort + 1 LUT blocks.
// Compact: inline deterministic sampled threshold; DENSE output via one global
// RMW per block. cand is NOT pre-zeroed: downstream masks by cnt, so stale
// slots beyond cnt are never observed.
__global__ void __launch_bounds__(512)
k_front(const float* __restrict__ cls0, const float* __restrict__ cls1,
        unsigned* __restrict__ cntG, unsigned long long* __restrict__ cand,
        const float* __restrict__ gt, const int* __restrict__ numgt,
        float4* __restrict__ sbox, unsigned short* __restrict__ sidxG,
        unsigned* __restrict__ lutG, float* __restrict__ maxwG) {
    unsigned tid = threadIdx.x, wave = tid >> 6, lane = tid & 63u;
    int bi = (int)blockIdx.x;

    if (bi < 144) {
        // ================== compact (lev0: bi<96, lev1: bi-96) ==================
        int lev = (bi < 96) ? 0 : 1;
        int bx  = (bi < 96) ? bi : bi - 96;
        const float* cls = lev ? cls1 : cls0;
        const float4* s4 = (const float4*)cls;
        unsigned nq4     = lev ? 3072u : 4096u;
        unsigned targetS = lev ? 5900u : 1966u;   // 11800 scaled by sample frac

        __shared__ unsigned h[8][256];
        __shared__ unsigned sfx[256];
        __shared__ unsigned sd[2];
        __shared__ unsigned lcnt, gbase;

        for (unsigned i = tid; i < 2048u; i += 512u) ((unsigned*)h)[i] = 0;
        __syncthreads();
        for (unsigned q = tid; q < nq4; q += 512u) {
            float4 v = s4[q];
            atomicAdd(&h[wave][f2ord(v.x) >> 24], 1u);
            atomicAdd(&h[wave][f2ord(v.y) >> 24], 1u);
            atomicAdd(&h[wave][f2ord(v.z) >> 24], 1u);
            atomicAdd(&h[wave][f2ord(v.w) >> 24], 1u);
        }
        __syncthreads();
        if (tid < 256) {
            unsigned s = 0;
            #pragma unroll
            for (int w = 0; w < 8; w++) s += h[w][tid];
            sfx[tid] = s;
        }
        __syncthreads();
        for (int off = 1; off < 256; off <<= 1) {   // inclusive suffix sum
            unsigned v = 0;
            if (tid < 256) v = sfx[tid] + ((tid + off < 256) ? sfx[tid + off] : 0u);
            __syncthreads();
            if (tid < 256) sfx[tid] = v;
            __syncthreads();
        }
        if (tid < 256) {
            unsigned suf = sfx[tid];
            unsigned sufN = (tid < 255) ? sfx[tid + 1] : 0u;
            if (suf >= targetS && sufN < targetS) { sd[0] = tid; sd[1] = targetS - sufN; }
        }
        for (unsigned i = tid; i < 2048u; i += 512u) ((unsigned*)h)[i] = 0;
        __syncthreads();
        unsigned tb = sd[0], remS = sd[1];
        for (unsigned q = tid; q < nq4; q += 512u) {
            float4 v = s4[q];
            unsigned k0 = f2ord(v.x), k1 = f2ord(v.y), k2 = f2ord(v.z), k3 = f2ord(v.w);
            if ((k0 >> 24) == tb) atomicAdd(&h[wave][(k0 >> 16) & 255u], 1u);
            if ((k1 >> 24) == tb) atomicAdd(&h[wave][(k1 >> 16) & 255u], 1u);
            if ((k2 >> 24) == tb) atomicAdd(&h[wave][(k2 >> 16) & 255u], 1u);
            if ((k3 >> 24) == tb) atomicAdd(&h[wave][(k3 >> 16) & 255u], 1u);
        }
        __syncthreads();
        if (tid < 256) {
            unsigned s = 0;
            #pragma unroll
            for (int w = 0; w < 8; w++) s += h[w][tid];
            sfx[tid] = s;
        }
        __syncthreads();
        for (int off = 1; off < 256; off <<= 1) {
            unsigned v = 0;
            if (tid < 256) v = sfx[tid] + ((tid + off < 256) ? sfx[tid + off] : 0u);
            __syncthreads();
            if (tid < 256) sfx[tid] = v;
            __syncthreads();
        }
        if (tid < 256) {
            unsigned suf = sfx[tid];
            unsigned sufN = (tid < 255) ? sfx[tid + 1] : 0u;
            if (suf >= remS && sufN < remS) sd[0] = tid;
        }
        if (tid == 0) lcnt = 0;
        __syncthreads();
        unsigned T = ((tb << 8) | sd[0]) << 16;

        unsigned n = lev ? (unsigned)N1 : (unsigned)N0;
        unsigned iters = lev ? 1u : 2u;
        unsigned long long l0 = 0, l1 = 0;
        unsigned c = 0;
        unsigned i = (unsigned)bx * 512u + tid;
        for (unsigned t = 0; t < iters; t++, i += 96u * 512u) {
            if (i < n) {
                unsigned key = f2ord(cls[i]);
                if (key >= T) {
                    unsigned long long v = ((unsigned long long)key << 32) | (unsigned)(~i);
                    if (c == 0) l0 = v; else l1 = v;
                    c++;
                }
            }
        }
        unsigned ls = 0;
        if (c) ls = atomicAdd(&lcnt, c);
        __syncthreads();
        if (tid == 0) gbase = lcnt ? atomicAdd(&cntG[lev], lcnt) : 0u;
        __syncthreads();
        unsigned b = gbase + ls;
        unsigned long long* cl = cand + (size_t)lev * ICAP;
        if (c > 0 && b + 0 < ICAP) cl[b + 0] = l0;
        if (c > 1 && b + 1 < ICAP) cl[b + 1] = l1;
    } else if (bi < 176) {
        // ===== GT sort by (f2ord(x1), idx): block owns 64 GTs, waves split j =====
        __shared__ __align__(16) unsigned keys[MAXGT];
        __shared__ unsigned prank[8][64];
        int ng = *numgt; if (ng > MAXGT) ng = MAXGT;
        for (int j = (int)tid; j < MAXGT; j += 512)
            keys[j] = (j < ng) ? f2ord(gt[(size_t)j * 5 + 0]) : 0xFFFFFFFFu;
        __syncthreads();
        int i = (bi - 144) * 64 + (int)lane;
        unsigned ki = (i < ng) ? keys[i] : 0xFFFFFFFFu;
        unsigned rank = 0;
        const uint4* k4 = (const uint4*)(keys + wave * 256u);
        #pragma unroll 8
        for (int q = 0; q < 64; q++) {
            uint4 kv = k4[q];
            int j = (int)(wave * 256u) + q * 4;
            rank += (kv.x < ki || (kv.x == ki && j + 0 < i)) ? 1u : 0u;
            rank += (kv.y < ki || (kv.y == ki && j + 1 < i)) ? 1u : 0u;
            rank += (kv.z < ki || (kv.z == ki && j + 2 < i)) ? 1u : 0u;
            rank += (kv.w < ki || (kv.w == ki && j + 3 < i)) ? 1u : 0u;
        }
        prank[wave][lane] = rank;
        __syncthreads();
        if (tid < 64) {
            int ii = (bi - 144) * 64 + (int)tid;
            if (ii < ng) {
                unsigned r = 0;
                #pragma unroll
                for (int w2 = 0; w2 < 8; w2++) r += prank[w2][tid];
                float x1 = gt[(size_t)ii * 5 + 0], y1 = gt[(size_t)ii * 5 + 1];
                float x2 = gt[(size_t)ii * 5 + 2], y2 = gt[(size_t)ii * 5 + 3];
                sbox[r]  = make_float4(x1, y1, x2 + 1.0f, y2 + 1.0f);  // upper +1
                sidxG[r] = (unsigned short)ii;
            }
        }
    } else {
        // ===== bucket LUT (exclusive prefix of x1 histogram) + maxw =====
        __shared__ unsigned hb[LUTN];
        __shared__ unsigned sc[LUTN];
        __shared__ float wm[8];
        int ng = *numgt; if (ng > MAXGT) ng = MAXGT;
        for (unsigned i = tid; i < LUTN; i += 512u) hb[i] = 0;
        __syncthreads();
        float w = 0.f;
        for (int j = (int)tid; j < ng; j += 512) {
            float x1 = gt[(size_t)j * 5 + 0];
            float x2 = gt[(size_t)j * 5 + 2];
            w = fmaxf(w, x2 - x1 + 1.0f);
            int b = (int)(x1 * (1.0f / LUTW));
            if (b < 0) b = 0; if (b > LUTN - 1) b = LUTN - 1;
            atomicAdd(&hb[b], 1u);
        }
        #pragma unroll
        for (int off = 32; off >= 1; off >>= 1) w = fmaxf(w, __shfl_xor(w, off));
        if (lane == 0) wm[wave] = w;
        __syncthreads();
        if (tid < LUTN) sc[tid] = hb[tid];
        __syncthreads();
        for (int off = 1; off < LUTN; off <<= 1) {
            unsigned v = 0;
            if (tid < LUTN) v = sc[tid] + ((int)tid - off >= 0 ? sc[tid - off] : 0u);
            __syncthreads();
            if (tid < LUTN) sc[tid] = v;
            __syncthreads();
        }
        if (tid < LUTN) lutG[tid] = (tid == 0) ? 0u : sc[tid - 1];
        if (tid == 0) {
            lutG[LUTN] = (unsigned)ng;
            float m = wm[0];
            #pragma unroll
            for (int k = 1; k < 8; k++) m = fmaxf(m, wm[k]);
            *maxwG = m;
        }
    }
}

// K2: partial counting-rank over DENSE candidates. j-tile masked by cnt so
// stale slots are inert (0-keys never beat real keys >= T > 0).
__global__ void __launch_bounds__(512)
k_rank(const unsigned long long* __restrict__ cand, const unsigned* __restrict__ cntG,
       unsigned short* __restrict__ part) {
    unsigned tid = threadIdx.x;
    int bi = (int)blockIdx.x;
    int lev = (bi < 352) ? 0 : 1;
    int idx = (bi < 352) ? bi : bi - 352;
    unsigned ic = (unsigned)(idx >> 5), jc = (unsigned)(idx & 31);
    unsigned cnt = cntG[lev]; if (cnt > ICAP) cnt = ICAP;
    unsigned cntP = (cnt + 63u) & ~63u;           // multiple of 64
    unsigned ibase = ic * 1536u;
    if (ibase >= cntP) return;                    // block-uniform
    const unsigned long long* cl = cand + (size_t)lev * ICAP;
    unsigned long long ci0 = cl[ibase + tid];
    unsigned long long ci1 = cl[ibase + tid + 512u];
    unsigned long long ci2 = cl[ibase + tid + 1024u];
    unsigned jch = cntP >> 5;                     // even (cntP % 64 == 0)
    unsigned j0 = jc * jch;
    unsigned lim2 = jch >> 1;                     // <= 264
    __shared__ __align__(16) unsigned long long tile[544];
    if (tid < lim2) {
        ulonglong2 v2 = ((const ulonglong2*)(cl + j0))[tid];
        unsigned jj = j0 + 2u * tid;
        if (jj >= cnt)      v2.x = 0ull;          // mask stale slots
        if (jj + 1u >= cnt) v2.y = 0ull;
        ((ulonglong2*)tile)[tid] = v2;
    }
    __syncthreads();
    unsigned rk0 = 0, rk1 = 0, rk2 = 0;
    const ulonglong2* t2 = (const ulonglong2*)tile;
    #pragma unroll 4
    for (unsigned t = 0; t < lim2; t++) {
        ulonglong2 cj = t2[t];
        rk0 += (cj.x > ci0) ? 1u : 0u; rk0 += (cj.y > ci0) ? 1u : 0u;
        rk1 += (cj.x > ci1) ? 1u : 0u; rk1 += (cj.y > ci1) ? 1u : 0u;
        rk2 += (cj.x > ci2) ? 1u : 0u; rk2 += (cj.y > ci2) ? 1u : 0u;
    }
    unsigned short* pp = part + (lev ? PARTL : 0) + (size_t)jc * ICAP + ibase + tid;
    pp[0]    = (unsigned short)rk0;
    pp[512]  = (unsigned short)rk1;
    pp[1024] = (unsigned short)rk2;
}

// K3: fused rank-scatter + decode + IoU argmax + targets. Wave owns 4 slots.
// Candidate slots gated by i < cnt (stale cand/part never observed).
__global__ void __launch_bounds__(512)
k_iou(Ptrs p, const unsigned long long* __restrict__ cand,
      const unsigned* __restrict__ cntG,
      const unsigned short* __restrict__ part,
      const float4* __restrict__ sbox, const unsigned short* __restrict__ sidxG,
      const unsigned* __restrict__ lutG, const float* __restrict__ maxwG,
      const float* __restrict__ gt, const int* __restrict__ numgt,
      float* __restrict__ out) {
    __shared__ float4 sg[MAXGT];              // sorted (x1,y1,x2+1,y2+1)  32 KiB
    __shared__ unsigned short sgi[MAXGT];     // 4 KiB
    __shared__ unsigned slut[LUTN + 1];
    int ng = *numgt; if (ng > MAXGT) ng = MAXGT;
    unsigned tid = threadIdx.x;
    for (int j = (int)tid; j < ng; j += 512) { sg[j] = sbox[j]; sgi[j] = sidxG[j]; }
    for (unsigned j = tid; j <= LUTN; j += 512u) slut[j] = lutG[j];
    float maxw = *maxwG;
    __syncthreads();

    unsigned wave = tid >> 6;
    int lane = (int)(tid & 63u);
    unsigned sbase = ((unsigned)blockIdx.x * 8u + wave) * 4u;

    int valid = 0, row = 0;
    float bx1 = 0.f, by1 = 0.f, bx2 = 0.f, by2 = 0.f;
    float dw = 1.f, dh = 1.f, dcx = 0.f, dcy = 0.f;
    if (lane < 4) {
        unsigned s = sbase + (unsigned)lane;
        int lev = 0, ai = 0;
        if (s < 2u * ICAP) {
            lev = (s >= (unsigned)ICAP) ? 1 : 0;
            unsigned i = lev ? (s - ICAP) : s;
            unsigned cnt = cntG[lev]; if (cnt > ICAP) cnt = ICAP;
            if (i < cnt) {
                unsigned long long v = cand[(size_t)lev * ICAP + i];
                const unsigned short* pp = part + (lev ? PARTL : 0) + i;
                unsigned rank = 0;
                #pragma unroll
                for (int j = 0; j < JSPLIT; j++)
                    rank += pp[(size_t)j * ICAP];
                if (rank < K_TOP) {
                    valid = 1;
                    row = lev * K_TOP + (int)rank;
                    ai = (int)~(unsigned)v;
                }
            }
        } else {
            int rr = (int)s - 2 * ICAP;          // < NSMALL by construction
            row = 2 * K_TOP + rr; valid = 1;
            if (rr < N2)           { lev = 2; ai = rr; }
            else if (rr < N2 + N3) { lev = 3; ai = rr - N2; }
            else                   { lev = 4; ai = rr - N2 - N3; }
        }
        if (valid) {
            float4 a4 = ((const float4*)p.anc[lev])[ai];
            float sc = p.cls[lev][ai];
            float4 r4 = *(const float4*)(p.reg[lev] + (size_t)ai * 8);
            dw = a4.z - a4.x + 1.0f;  dh = a4.w - a4.y + 1.0f;
            dcx = a4.x + 0.5f * dw;   dcy = a4.y + 0.5f * dh;
            float pcx = r4.x * dw + dcx, pcy = r4.y * dh + dcy;
            float pw = expf(r4.z) * dw,  ph = expf(r4.w) * dh;
            bx1 = pcx - 0.5f * pw;    by1 = pcy - 0.5f * ph;
            bx2 = pcx + 0.5f * pw - 1.0f;
            by2 = pcy + 0.5f * ph - 1.0f;
            float* o = out + (size_t)row * 10;
            o[0] = bx1; o[1] = by1; o[2] = bx2; o[3] = by2;
            o[4] = 1.0f / (1.0f + expf(-sc));
            o[5] = 1.0f;
        }
    }

    #pragma unroll
    for (int k = 0; k < 4; k++) {
        int vk = __shfl(valid, k, 64);
        if (!vk) continue;                       // wave-uniform
        float kx1 = __shfl(bx1, k, 64), ky1 = __shfl(by1, k, 64);
        float kx2 = __shfl(bx2, k, 64), ky2 = __shfl(by2, k, 64);
        float A = (kx2 - kx1 + 1.0f) * (ky2 - ky1 + 1.0f);
        float x2p = kx2 + 1.0f, y2p = ky2 + 1.0f;
        float vlo = kx1 - maxw - 1.0f;
        float vhi = kx2 + 2.0f;
        int blo = (vlo <= 0.f) ? 0 : (int)(vlo * (1.0f / LUTW));
        if (blo > LUTN - 1) blo = LUTN - 1;
        int bhi = (vhi <= 0.f) ? 0 : ((int)(vhi * (1.0f / LUTW)) + 1);
        if (bhi > LUTN) bhi = LUTN;
        int lo = (int)slut[blo], hi = (int)slut[bhi];

        // iou_a > iou_b <=> I_a*S_b > I_b*S_a  (S = areaBox + areaGT)
        float I = 0.f, S = 1.f;
        int arg = (lane == 0) ? 0 : 0x7FFFFFFF;
        for (int t = lo + lane; t < hi; t += 64) {
            float4 gb = sg[t];
            float iw = fminf(x2p, gb.z) - fmaxf(kx1, gb.x); iw = fmaxf(iw, 0.f);
            float ih = fminf(y2p, gb.w) - fmaxf(ky1, gb.y); ih = fmaxf(ih, 0.f);
            float Ii = iw * ih;
            float Ss = A + (gb.z - gb.x) * (gb.w - gb.y);   // area from folded corners
            float xs = Ii * S, ys = I * Ss;
            int gi = (int)sgi[t];
            if (xs > ys || (xs == ys && gi < arg)) { I = Ii; S = Ss; arg = gi; }
        }
        #pragma unroll
        for (int off = 1; off < 64; off <<= 1) {   // max iou, tie -> min orig idx
            float oI = __shfl_xor(I, off), oS = __shfl_xor(S, off);
            int   oa = __shfl_xor(arg, off);
            float x = oI * S, y = I * oS;
            if (x > y || (x == y && oa < arg)) { I = oI; S = oS; arg = oa; }
        }
        if (lane == k) {
            if (arg >= ng) arg = 0;
            const float* gb = gt + (size_t)arg * 5;   // ORIGINAL coords (exact)
            float gx1 = gb[0], gy1 = gb[1], gx2 = gb[2], gy2 = gb[3];
            float gw = gx2 - gx1 + 1.0f, gh = gy2 - gy1 + 1.0f;
            float gcx = gx1 + 0.5f * gw,  gcy = gy1 + 0.5f * gh;
            float* o = out + (size_t)row * 10;
            o[6] = (gcx - dcx) / dw;
            o[7] = (gcy - dcy) / dh;
            o[8] = logf(gw / dw);
            o[9] = logf(gh / dh);
        }
    }
}

extern "C" void kernel_launch(void* const* d_in, const int* in_sizes, int n_in,
                              void* d_out, int out_size, void* d_ws, size_t ws_size,
                              hipStream_t stream) {
    Ptrs p;
    bool interleaved = (in_sizes[2] == N0 * 8);
    for (int l = 0; l < 5; l++) {
        if (interleaved) {
            p.anc[l] = (const float*)d_in[3 * l + 0];
            p.cls[l] = (const float*)d_in[3 * l + 1];
            p.reg[l] = (const float*)d_in[3 * l + 2];
        } else {
            p.anc[l] = (const float*)d_in[l];
            p.cls[l] = (const float*)d_in[5 + l];
            p.reg[l] = (const float*)d_in[10 + l];
        }
    }
    const float* gt    = (const float*)d_in[15];
    const int*   numgt = (const int*)d_in[16];

    char* ws = (char*)d_ws;
    size_t off = 0;
    unsigned* cntG = (unsigned*)(ws + off);                      off += 256;
    unsigned long long* cand = (unsigned long long*)(ws + off);  off += (size_t)2 * ICAP * 8;           // 264 KiB
    unsigned short* part = (unsigned short*)(ws + off);          off += (size_t)JSPLIT * 2 * ICAP * 2;  // 2.06 MiB
    float4* sbox = (float4*)(ws + off);                          off += (size_t)MAXGT * 16;             // 32 KiB
    unsigned short* sidxG = (unsigned short*)(ws + off);         off += (size_t)MAXGT * 2;              // 4 KiB
    unsigned* lutG = (unsigned*)(ws + off);                      off += (size_t)(LUTN + 4) * 4;
    float* maxwG = (float*)(ws + off);                           off += 256;

    float* out = (float*)d_out;

    // zero ONLY the 2 counters (8 bytes) — stale cand/part are masked by cnt
    hipMemsetAsync(d_ws, 0, 8, stream);
    k_front<<<dim3(177), dim3(512), 0, stream>>>(p.cls[0], p.cls[1], cntG, cand,
                                                 gt, numgt, sbox, sidxG, lutG, maxwG);
    k_rank<<<dim3(704), dim3(512), 0, stream>>>(cand, cntG, part);
    k_iou<<<dim3(SLOTS / 32), dim3(512), 0, stream>>>(p, cand, cntG, part, sbox, sidxG,
                                                      lutG, maxwG, gt, numgt, out);
}